// Round 21
// baseline (233.626 us; speedup 1.0000x reference)
//
#include <hip/hip_runtime.h>
#include <cstdint>

#define C_ 128
#define L_ 16
#define G_ 4
#define H_ 56
#define W_ 56
#define HW_ 3136
#define NPAIR_ 8                   // 8 pairs x 4 channels = 32
#define NR_ 5                      // halo rows per wave per channel
#define PBUF_F 1280                // pair buffer: [A 512][B 512][Atail 128][Btail 128]
#define WL_F 2048                  // weights [c(32)][dy(8)][dx(8)], 1/32 folded
#define LDS_F (WL_F + 4 * 2 * PBUF_F)  // 12288 floats = 49152 B -> 3 blocks/CU

typedef float f4 __attribute__((ext_vector_type(4)));
typedef __attribute__((address_space(3))) uint32_t lds_u32;
typedef const __attribute__((address_space(1))) uint32_t glb_u32;

// r16 base + PAIR PROCESSING: 4 channels per vmcnt window (was 2) -> half
// the wait points, 448-inst FMA runs per wait (~900 cyc, covers all
// latencies). Dummy-free 5-call staging: pair-buf layout [A rows0-7][B
// rows0-7][A rows8-9][B rows8-9] makes task tau -> LDS float tau*4 linear
// across all 320 tasks (call 4 carries both chunks' tail rows; no overflow
// lanes, no dummy writes, no same-address DMA races).
// vmcnt arithmetic: top queue = [stage(pair j):5]; issue x1A(4); vmcnt(4)
// drains stage exactly. x1B issues BEFORE stage(pair j+1), so consuming it
// never drains the prefetch. Weights in LDS [c][dy][8] (2 x b128/chunk,
// 1/32 folded at fill). XOR swizzle vb = sb ^ (rg&7) both-sides as always.
__global__ __launch_bounds__(256, 2)
void wcorr(const float* __restrict__ x, const float* __restrict__ wgt,
           float* __restrict__ out, const float* __restrict__ zsrc) {
  __shared__ float lds[LDS_F];

  int bid = blockIdx.x;
  // bijective XCD swizzle: nwg = 7168 = 8*896; htile fastest (halo-row reuse)
  int wid = (bid & 7) * 896 + (bid >> 3);
  int htile = wid % 14;
  int rest = wid / 14;             // (b*4+g)*16 + t
  int t = rest & 15;
  int bg = rest >> 4;
  int g = bg & 3;
  int b = bg >> 2;
  int h0 = htile * 4;

  int tid = threadIdx.x;
  int lane = tid & 63;
  int wvu = __builtin_amdgcn_readfirstlane(tid >> 6);  // wave 0..3 (uniform)
  int tx = tid & 7;
  int slot = tid >> 3;
  int h = slot & 3;
  int dy = slot >> 2;              // wave w holds dy in {2w, 2w+1}
  bool active = (dy < 7) && (tx < 7);
  int dyc = dy < 7 ? dy : 6;
  int txc = tx < 7 ? tx : 6;
  int r = h + dyc;                 // global halo row 0..9
  int t1 = t > 0 ? t - 1 : 0;
  int w0 = 8 * txc;

  const size_t cstride = (size_t)L_ * HW_;
  const float* xg = x + ((size_t)b * C_ + (size_t)g * 32) * cstride;

  // ---- staging pointers: 5 full-wave calls per pair, task tau = lane+64m.
  // tau<128: chunk A rho=tau>>4; tau<256: chunk B rho=(tau-128)>>4;
  // tau>=256: q=tau-256, chunk=q>>5, rho=8+((q&31)>>4). sb=tau&15.
  // ci = rho>=5, lrr = rho-5ci, rg = 2w+lrr, vb = sb^(rg&7).
  auto mkstage = [&](int m, const float*& sp, ptrdiff_t& inc) {
    int tau = lane + m * 64;
    int chunk, rho;
    if (tau < 128)      { chunk = 0; rho = tau >> 4; }
    else if (tau < 256) { chunk = 1; rho = (tau - 128) >> 4; }
    else { int q = tau - 256; chunk = q >> 5; rho = 8 + ((q & 31) >> 4); }
    int sb = tau & 15;
    int ci = (rho >= NR_) ? 1 : 0;
    int lrr = rho - ci * NR_;
    int rg = 2 * wvu + lrr;
    int vb = sb ^ (rg & 7);
    int hh = h0 - 3 + rg;
    bool ok = (vb >= 1) && (vb <= 14) && (hh >= 0) && (hh < H_);
    sp = ok ? (xg + (size_t)(chunk * 2 + ci) * cstride + (size_t)t * HW_
                  + hh * W_ + (vb * 4 - 4))
            : (zsrc + (lane & 15) * 4);
    inc = ok ? (ptrdiff_t)(4 * cstride) : 0;   // 4 channels per pair
  };
  const float *sp0, *sp1, *sp2, *sp3, *sp4;
  ptrdiff_t in0, in1, in2, in3, in4;
  mkstage(0, sp0, in0); mkstage(1, sp1, in1); mkstage(2, sp2, in2);
  mkstage(3, sp3, in3); mkstage(4, sp4, in4);

  float* lds_pair = &lds[WL_F + wvu * (2 * PBUF_F)];
  auto stage_pair = [&](int pb) {
    float* db = lds_pair + pb * PBUF_F;
    __builtin_amdgcn_global_load_lds((glb_u32*)sp0, (lds_u32*)(db + 0),    16, 0, 0);
    __builtin_amdgcn_global_load_lds((glb_u32*)sp1, (lds_u32*)(db + 256),  16, 0, 0);
    __builtin_amdgcn_global_load_lds((glb_u32*)sp2, (lds_u32*)(db + 512),  16, 0, 0);
    __builtin_amdgcn_global_load_lds((glb_u32*)sp3, (lds_u32*)(db + 768),  16, 0, 0);
    __builtin_amdgcn_global_load_lds((glb_u32*)sp4, (lds_u32*)(db + 1024), 16, 0, 0);
    sp0 += in0; sp1 += in1; sp2 += in2; sp3 += in3; sp4 += in4;
  };

  stage_pair(0);   // pair 0 -> buf 0 (drained by the weights barrier)

  // ---- stage weights once, transposed [c][dy][8], 1/32 folded ----
  {
    const float sc = 1.0f / 32.0f;
    const float* wsrc = wgt + (size_t)(g * 32) * (L_ * 49) + t * 49;
    #pragma unroll
    for (int j = 0; j < 8; ++j) {
      int idx = tid + j * 256;
      int c = idx >> 6;
      int rem = idx & 63;
      int dyy = rem >> 3, dxx = rem & 7;
      float v = 0.0f;
      if (dyy < 7 && dxx < 7)
        v = wsrc[(size_t)c * (L_ * 49) + dyy * 7 + dxx] * sc;
      lds[idx] = v;
    }
  }

  // per-lane static read offsets within a pair buffer (floats):
  // rho_ci = ci*5 + (r - 2w); off = rho<8 ? chunk*512 + rho*64
  //                                       : 1024 + chunk*128 + (rho-8)*64
  int lr0 = r - 2 * wvu;           // 0..4 (ci=0)
  int rho1 = NR_ + lr0;            // 5..9 (ci=1)
  int offA0 = lr0 * 64;
  int offA1 = (rho1 < 8) ? rho1 * 64 : 1024 + (rho1 - 8) * 64;
  int offB0 = 512 + lr0 * 64;
  int offB1 = (rho1 < 8) ? 512 + rho1 * 64 : 1152 + (rho1 - 8) * 64;

  // x1 pointers for the pair's 4 channels
  const float* x1p0 = xg + (size_t)t1 * HW_ + (size_t)(h0 + h) * W_ + w0;
  const float* x1p1 = x1p0 + cstride;
  const float* x1p2 = x1p0 + 2 * cstride;
  const float* x1p3 = x1p0 + 3 * cstride;

  float acc[7][8];
  #pragma unroll
  for (int i = 0; i < 7; ++i)
    #pragma unroll
    for (int p = 0; p < 8; ++p) acc[i][p] = 0.0f;

  __syncthreads();   // weights visible; drains prologue stage; ONLY barrier

  int s = r & 7;
  #pragma unroll 1
  for (int j = 0; j < NPAIR_; ++j) {
    int c0 = j * 4;
    float* pb = lds_pair + (j & 1) * PBUF_F;

    // x1 for chunk A (channels c0, c0+1): queue = [stage(j):5][x1A:4]
    f4 aA0 = *(const f4*)(x1p0);
    f4 aA1 = *(const f4*)(x1p0 + 4);
    f4 aA2 = *(const f4*)(x1p1);
    f4 aA3 = *(const f4*)(x1p1 + 4);

    __builtin_amdgcn_sched_barrier(0);
    asm volatile("s_waitcnt vmcnt(4)" ::: "memory");  // stage(pair j) landed
    __builtin_amdgcn_sched_barrier(0);

    // ds reads chunk A + weights A
    const f4* xsA0 = (const f4*)(pb + offA0);
    const f4* xsA1 = (const f4*)(pb + offA1);
    f4 qa0 = xsA0[(2 * txc + 0) ^ s];
    f4 qa1 = xsA0[(2 * txc + 1) ^ s];
    f4 qa2 = xsA0[(2 * txc + 2) ^ s];
    f4 qa3 = xsA0[(2 * txc + 3) ^ s];
    f4 qb0 = xsA1[(2 * txc + 0) ^ s];
    f4 qb1 = xsA1[(2 * txc + 1) ^ s];
    f4 qb2 = xsA1[(2 * txc + 2) ^ s];
    f4 qb3 = xsA1[(2 * txc + 3) ^ s];
    const f4* wlA0 = (const f4*)&lds[(c0 + 0) * 64 + dyc * 8];
    const f4* wlA1 = (const f4*)&lds[(c0 + 1) * 64 + dyc * 8];
    f4 wA00 = wlA0[0], wA01 = wlA0[1];
    f4 wA10 = wlA1[0], wA11 = wlA1[1];

    // x1 for chunk B BEFORE the stage issue (so its consumption never
    // drains the prefetch)
    f4 aB0 = *(const f4*)(x1p2);
    f4 aB1 = *(const f4*)(x1p2 + 4);
    f4 aB2 = *(const f4*)(x1p3);
    f4 aB3 = *(const f4*)(x1p3 + 4);
    x1p0 += 4 * cstride; x1p1 += 4 * cstride;
    x1p2 += 4 * cstride; x1p3 += 4 * cstride;

    if (j + 1 < NPAIR_) stage_pair((j & 1) ^ 1);   // prefetch pair j+1

    __builtin_amdgcn_s_setprio(1);
    #pragma unroll
    for (int ci = 0; ci < 2; ++ci) {
      f4 Q0 = ci ? qb0 : qa0, Q1 = ci ? qb1 : qa1;
      f4 Q2 = ci ? qb2 : qa2, Q3 = ci ? qb3 : qa3;
      f4 W0 = ci ? wA10 : wA00, W1 = ci ? wA11 : wA01;
      f4 A0 = ci ? aA2 : aA0, A1 = ci ? aA3 : aA1;
      float w7[7] = {W0.x, W0.y, W0.z, W0.w, W1.x, W1.y, W1.z};
      float rr_[16] = {Q0.x, Q0.y, Q0.z, Q0.w, Q1.x, Q1.y, Q1.z, Q1.w,
                       Q2.x, Q2.y, Q2.z, Q2.w, Q3.x, Q3.y, Q3.z, Q3.w};
      float x1v[8] = {A0.x, A0.y, A0.z, A0.w, A1.x, A1.y, A1.z, A1.w};
      #pragma unroll
      for (int dxx = 0; dxx < 7; ++dxx)
        #pragma unroll
        for (int p = 0; p < 8; ++p)
          acc[dxx][p] = fmaf(w7[dxx], x1v[p] * rr_[p + dxx + 1], acc[dxx][p]);
    }
    __builtin_amdgcn_s_setprio(0);

    // ds reads chunk B + weights B, then FMA B
    const f4* xsB0 = (const f4*)(pb + offB0);
    const f4* xsB1 = (const f4*)(pb + offB1);
    f4 qc0 = xsB0[(2 * txc + 0) ^ s];
    f4 qc1 = xsB0[(2 * txc + 1) ^ s];
    f4 qc2 = xsB0[(2 * txc + 2) ^ s];
    f4 qc3 = xsB0[(2 * txc + 3) ^ s];
    f4 qd0 = xsB1[(2 * txc + 0) ^ s];
    f4 qd1 = xsB1[(2 * txc + 1) ^ s];
    f4 qd2 = xsB1[(2 * txc + 2) ^ s];
    f4 qd3 = xsB1[(2 * txc + 3) ^ s];
    const f4* wlB0 = (const f4*)&lds[(c0 + 2) * 64 + dyc * 8];
    const f4* wlB1 = (const f4*)&lds[(c0 + 3) * 64 + dyc * 8];
    f4 wB00 = wlB0[0], wB01 = wlB0[1];
    f4 wB10 = wlB1[0], wB11 = wlB1[1];

    __builtin_amdgcn_s_setprio(1);
    #pragma unroll
    for (int ci = 0; ci < 2; ++ci) {
      f4 Q0 = ci ? qd0 : qc0, Q1 = ci ? qd1 : qc1;
      f4 Q2 = ci ? qd2 : qc2, Q3 = ci ? qd3 : qc3;
      f4 W0 = ci ? wB10 : wB00, W1 = ci ? wB11 : wB01;
      f4 A0 = ci ? aB2 : aB0, A1 = ci ? aB3 : aB1;
      float w7[7] = {W0.x, W0.y, W0.z, W0.w, W1.x, W1.y, W1.z};
      float rr_[16] = {Q0.x, Q0.y, Q0.z, Q0.w, Q1.x, Q1.y, Q1.z, Q1.w,
                       Q2.x, Q2.y, Q2.z, Q2.w, Q3.x, Q3.y, Q3.z, Q3.w};
      float x1v[8] = {A0.x, A0.y, A0.z, A0.w, A1.x, A1.y, A1.z, A1.w};
      #pragma unroll
      for (int dxx = 0; dxx < 7; ++dxx)
        #pragma unroll
        for (int p = 0; p < 8; ++p)
          acc[dxx][p] = fmaf(w7[dxx], x1v[p] * rr_[p + dxx + 1], acc[dxx][p]);
    }
    __builtin_amdgcn_s_setprio(0);
  }

  if (active) {
    #pragma unroll
    for (int dxx = 0; dxx < 7; ++dxx) {
      int och = (dy * 7 + dxx) * G_ + g;
      float* op = out + (((size_t)b * 196 + och) * L_ + t) * (size_t)HW_
                      + (size_t)(h0 + h) * W_ + w0;
      f4 o0 = {acc[dxx][0], acc[dxx][1], acc[dxx][2], acc[dxx][3]};
      f4 o1 = {acc[dxx][4], acc[dxx][5], acc[dxx][6], acc[dxx][7]};
      __builtin_nontemporal_store(o0, (f4*)op);
      __builtin_nontemporal_store(o1, (f4*)(op + 4));
    }
  }
}

extern "C" void kernel_launch(void* const* d_in, const int* in_sizes, int n_in,
                              void* d_out, int out_size, void* d_ws, size_t ws_size,
                              hipStream_t stream) {
  const float* x = (const float*)d_in[0];
  const float* w = (const float*)d_in[1];
  float* o = (float*)d_out;
  // 256 B zeros region for redirected (pad/OOB) staging lanes
  hipMemsetAsync(d_ws, 0, 256, stream);
  dim3 grid(7168), block(256);
  hipLaunchKernelGGL(wcorr, grid, block, 0, stream, x, w, o, (const float*)d_ws);
}